// Round 7
// baseline (218.758 us; speedup 1.0000x reference)
//
#include <hip/hip_runtime.h>
#include <hip/hip_bf16.h>

using floatx4 = __attribute__((ext_vector_type(4))) float;
using bf16x8  = __attribute__((ext_vector_type(8))) __bf16;
using uintx4  = __attribute__((ext_vector_type(4))) unsigned int;

#define DEV __device__ __forceinline__

DEV unsigned short f2bf(float f){
  unsigned u = __float_as_uint(f);
  u = (u + 0x7FFFu + ((u >> 16) & 1u)) >> 16;   // RNE
  return (unsigned short)u;
}
DEV float bf2f(unsigned short h){ return __uint_as_float(((unsigned)h) << 16); }

DEV void gload_lds16(const void* g, void* l){
  __builtin_amdgcn_global_load_lds((const __attribute__((address_space(1))) void*)g,
                                   (__attribute__((address_space(3))) void*)l, 16, 0, 0);
}

DEV void atomicMaxF(float* a, float v){
  if (v >= 0.f) atomicMax((int*)a, __float_as_int(v));
  else          atomicMin((unsigned int*)a, __float_as_uint(v));
}

#define SBAR do{ __builtin_amdgcn_sched_barrier(0); __builtin_amdgcn_s_barrier(); \
                 __builtin_amdgcn_sched_barrier(0); }while(0)

// ---------------------------------------------------------------------------
// prep: all f32->bf16 casts + zero-init, one launch.
__global__ __launch_bounds__(256) void k_prep(
    const float* __restrict__ query, const float* __restrict__ Wq,
    const float* __restrict__ Wk, const float* __restrict__ Wv,
    const float* __restrict__ Wo, const float* __restrict__ proj,
    unsigned short* __restrict__ qbf, unsigned short* __restrict__ wqb,
    unsigned short* __restrict__ wkb, unsigned short* __restrict__ wvb,
    unsigned short* __restrict__ wob, unsigned short* __restrict__ pjb,
    float* __restrict__ esum, float* __restrict__ vsum, float* __restrict__ stab)
{
  const int bid = blockIdx.x, tid = threadIdx.x;
  const float* s; unsigned short* d; int i, stride, n4;
  if (bid < 1024){ s = query; d = qbf; i = bid*256 + tid; stride = 262144; n4 = 4194304; }
  else if (bid < 1280){
    int w = (bid - 1024) >> 6;
    s = (w==0)?Wq:(w==1)?Wk:(w==2)?Wv:Wo;
    d = (w==0)?wqb:(w==1)?wkb:(w==2)?wvb:wob;
    i = ((bid-1024)&63)*256 + tid; stride = 16384; n4 = 262144;
  } else if (bid < 1296){ s = proj; d = pjb; i = (bid-1280)*256 + tid; stride = 4096; n4 = 16384; }
  else {
    for (int k = tid; k < 4096; k += 256){ esum[k] = 0.f; vsum[k] = 0.f; }
    if (tid < 64) stab[tid] = -1e30f;
    return;
  }
  for (; i < n4; i += stride){
    float4 v = ((const float4*)s)[i];
    ushort4 o;
    o.x = f2bf(v.x); o.y = f2bf(v.y); o.z = f2bf(v.z); o.w = f2bf(v.w);
    ((ushort4*)d)[i] = o;
  }
}

// ---------------------------------------------------------------------------
// 256x256 GEMM, BK=64, 2 LDS buffers, 4 phases/K-tile, per-phase stage units,
// counted vmcnt(4), XOR slot swizzle, LDS-staged epilogue.
// 1D grid + bijective XCD-chunked remap (m-major within chunk): the N-panel
// blocks sharing an A-panel run concurrently on ONE XCD -> A hits its L2.
template<int OUTMODE>
__global__ __launch_bounds__(512, 1) void gemm256(
    const unsigned short* __restrict__ A,
    const unsigned short* __restrict__ W,
    const float* __restrict__ bias0, const float* __restrict__ bias1,
    const float* __restrict__ bias2,
    unsigned short* __restrict__ out0, unsigned short* __restrict__ out1,
    unsigned short* __restrict__ out2,
    float* __restrict__ outf, int M, int Nout, int K)
{
  __shared__ __align__(16) char lds[131072];
  const int tid  = threadIdx.x;
  const int wid  = tid >> 6, lane = tid & 63;
  const int wr   = wid >> 2, wc = wid & 3;
  const int fr   = lane & 15, kch = lane >> 4;

  // XCD-chunked bijective remap (requires nwg % 8 == 0), m-major decode
  const int ntn = Nout >> 8;
  const int nwg = (M >> 8) * ntn;
  const int q8  = nwg >> 3;
  const int flat = blockIdx.x;
  const int newf = (flat & 7) * q8 + (flat >> 3);
  const int m0   = (newf / ntn) * 256, n0 = (newf % ntn) * 256;

  const int NU   = (K >> 6) * 4;                  // total stage units
  const size_t Kb = (size_t)K * 2;

  // staging lane constants: 4 lanes/row (64B khalf), swizzled source slot
  const int ssw = (((lane & 3) ^ ((lane >> 3) & 3))) * 16;
  const char* Arow = (const char*)A + (size_t)(m0 + wid*16 + (lane >> 2))*Kb + ssw;
  const char* Brow = (const char*)W + (size_t)(n0 + wid*16 + (lane >> 2))*Kb + ssw;

  auto stage = [&](int u){
    if (u >= NU) return;
    int T = u >> 2, q = u & 3, isB = q & 1, s = q >> 1;
    char* dst = lds + (T & 1)*65536 + isB*32768 + s*16384 + wid*1024;
    const char* src = (isB ? Brow : Arow) + (size_t)T*128 + s*64;
    gload_lds16(src, dst);
    gload_lds16(src + 128*Kb, dst + 8192);
  };

  // prologue: tile 0's 4 units (8 loads/wave)
  stage(0); stage(1); stage(2); stage(3);

  const int rkey = (fr >> 1) & 3;
  const int aBase = (wr*128 + fr)*64 + (kch ^ rkey)*16;
  const int bBase = 32768 + (wc*64 + fr)*64 + (kch ^ rkey)*16;
  floatx4 acc[8][4] = {};
  bf16x8 a[4], bq[4];

  const int NTt = K >> 6;
  for (int T = 0; T < NTt; ++T){
    const char* buf = lds + (T & 1)*65536;
    // ---- phase 0: s=0, mt 0-3 (+ B s0)
    asm volatile("s_waitcnt vmcnt(4)" ::: "memory");
    SBAR;
    #pragma unroll
    for (int mt = 0; mt < 4; ++mt) a[mt]  = *(const bf16x8*)(buf + aBase + mt*1024);
    #pragma unroll
    for (int nt = 0; nt < 4; ++nt) bq[nt] = *(const bf16x8*)(buf + bBase + nt*1024);
    stage(T*4 + 4);
    __builtin_amdgcn_s_setprio(1);
    #pragma unroll
    for (int mt = 0; mt < 4; ++mt)
      #pragma unroll
      for (int nt = 0; nt < 4; ++nt)
        acc[mt][nt] = __builtin_amdgcn_mfma_f32_16x16x32_bf16(a[mt], bq[nt], acc[mt][nt], 0, 0, 0);
    __builtin_amdgcn_s_setprio(0);
    // ---- phase 1: s=0, mt 4-7
    #pragma unroll
    for (int mt = 0; mt < 4; ++mt) a[mt] = *(const bf16x8*)(buf + aBase + (4+mt)*1024);
    stage(T*4 + 5);
    __builtin_amdgcn_s_setprio(1);
    #pragma unroll
    for (int mt = 0; mt < 4; ++mt)
      #pragma unroll
      for (int nt = 0; nt < 4; ++nt)
        acc[4+mt][nt] = __builtin_amdgcn_mfma_f32_16x16x32_bf16(a[mt], bq[nt], acc[4+mt][nt], 0, 0, 0);
    __builtin_amdgcn_s_setprio(0);
    // ---- phase 2: s=1, mt 0-3 (+ B s1)
    if (T + 1 < NTt) asm volatile("s_waitcnt vmcnt(4)" ::: "memory");
    else             asm volatile("s_waitcnt vmcnt(0)" ::: "memory");
    SBAR;
    #pragma unroll
    for (int mt = 0; mt < 4; ++mt) a[mt]  = *(const bf16x8*)(buf + 16384 + aBase + mt*1024);
    #pragma unroll
    for (int nt = 0; nt < 4; ++nt) bq[nt] = *(const bf16x8*)(buf + 16384 + bBase + nt*1024);
    stage(T*4 + 6);
    __builtin_amdgcn_s_setprio(1);
    #pragma unroll
    for (int mt = 0; mt < 4; ++mt)
      #pragma unroll
      for (int nt = 0; nt < 4; ++nt)
        acc[mt][nt] = __builtin_amdgcn_mfma_f32_16x16x32_bf16(a[mt], bq[nt], acc[mt][nt], 0, 0, 0);
    __builtin_amdgcn_s_setprio(0);
    // ---- phase 3: s=1, mt 4-7
    #pragma unroll
    for (int mt = 0; mt < 4; ++mt) a[mt] = *(const bf16x8*)(buf + 16384 + aBase + (4+mt)*1024);
    stage(T*4 + 7);
    __builtin_amdgcn_s_setprio(1);
    #pragma unroll
    for (int mt = 0; mt < 4; ++mt)
      #pragma unroll
      for (int nt = 0; nt < 4; ++nt)
        acc[4+mt][nt] = __builtin_amdgcn_mfma_f32_16x16x32_bf16(a[mt], bq[nt], acc[4+mt][nt], 0, 0, 0);
    __builtin_amdgcn_s_setprio(0);
  }

  // ---- epilogue: stage through LDS for full-line global writes.
  SBAR;
  if (OUTMODE == 0){
    const int which = n0 >> 10;
    const float* bb = (which == 0) ? bias0 : (which == 1) ? bias1 : bias2;
    unsigned short* oo = (which == 0) ? out0 : (which == 1) ? out1 : out2;
    unsigned short* Lt = (unsigned short*)lds;   // [256][256] bf16, col-XOR swz
    #pragma unroll
    for (int nf = 0; nf < 4; ++nf){
      int col = wc*64 + nf*16 + fr;
      float bv = bb[(n0 + col) & 1023];
      #pragma unroll
      for (int mf = 0; mf < 8; ++mf)
        #pragma unroll
        for (int r = 0; r < 4; ++r){
          int row = wr*128 + mf*16 + kch*4 + r;
          Lt[row*256 + (col ^ (((row >> 2) & 3) << 4))] = f2bf(acc[mf][nf][r] + bv);
        }
    }
    SBAR;
    const int orow = tid >> 5, oj = tid & 31;
    #pragma unroll
    for (int p = 0; p < 16; ++p){
      int row = p*16 + orow;
      uintx4 v = *(const uintx4*)(Lt + row*256 + ((oj*8) ^ (((row >> 2) & 3) << 4)));
      *(uintx4*)(oo + (size_t)(m0 + row)*1024 + (n0 & 1023) + oj*8) = v;
    }
  } else {
    float* Lf = (float*)lds;                     // [128][256] f32, 2 passes
    #pragma unroll
    for (int p = 0; p < 2; ++p){
      if (wr == p){
        #pragma unroll
        for (int nf = 0; nf < 4; ++nf){
          int col = wc*64 + nf*16 + fr;
          float bv = bias0[n0 + col];
          #pragma unroll
          for (int mf = 0; mf < 8; ++mf)
            #pragma unroll
            for (int r = 0; r < 4; ++r){
              int row = mf*16 + kch*4 + r;       // 0..127
              Lf[row*256 + (col ^ (((row >> 2) & 3) << 4))] = acc[mf][nf][r] + bv;
            }
        }
      }
      SBAR;
      const int oj = tid & 63;
      #pragma unroll
      for (int pp = 0; pp < 16; ++pp){
        int row = pp*8 + wid;
        uintx4 v = *(const uintx4*)(Lf + row*256 + ((oj*4) ^ (((row >> 2) & 3) << 4)));
        *(uintx4*)(outf + (size_t)(m0 + p*128 + row)*Nout + n0 + oj*4) = v;
      }
      SBAR;
    }
  }
}

// ---- FAVOR+ -----------------------------------------------------------------
#define CS 0.35355339059327373f   /* 64^-0.25 */

// Fused K-side FAVOR + V-transpose + kv-contraction. Block = (ks, bh); loops
// 4 chunks of 128 rows. e-features and V^T live only in LDS; kv partials
// accumulate in registers across chunks. Writes: kvp[ks][bh][64][64] f32 only.
__global__ __launch_bounds__(256) void k_fkv(const unsigned short* __restrict__ Kb,
                                             const unsigned short* __restrict__ Vb,
                                             const unsigned short* __restrict__ Pb,
                                             float* __restrict__ kvp,
                                             float* __restrict__ esum,
                                             float* __restrict__ vsum,
                                             float* __restrict__ stab,
                                             int Nn, int D, int H)
{
  __shared__ __align__(16) unsigned short Ks[128*64];
  __shared__ __align__(16) unsigned short Ps[64*64];
  __shared__ __align__(16) unsigned short Te[64*136];
  __shared__ __align__(16) unsigned short Tv[64*136];
  __shared__ float diag_s[128];
  __shared__ float wm[4];
  const int tid = threadIdx.x, wave = tid >> 6, lane = tid & 63;
  const int ksb = blockIdx.x, bh = blockIdx.y, h = bh % H, b = bh / H;
  const int fr = lane & 15, kch = lane >> 4;
  const int sr = lane >> 3, sc = (lane & 7) * 8;
  float esum_r = 0.f, vsum_r = 0.f, mx = -1e30f;
  floatx4 acc_kv[4] = {};

  for (int c = 0; c < 4; ++c){
    const int n0c = ksb*512 + c*128;
    __syncthreads();                        // prev chunk fully consumed
    #pragma unroll
    for (int q = 0; q < 4; ++q){
      int seg = wave*4 + q;
      gload_lds16(Kb + ((size_t)b*Nn + n0c + seg*8 + sr)*D + h*64 + sc, (char*)Ks + seg*1024);
    }
    if (c == 0){
      #pragma unroll
      for (int q = 0; q < 2; ++q){
        int seg = wave*2 + q;
        gload_lds16(Pb + (size_t)h*4096 + seg*512 + lane*8, (char*)Ps + seg*1024);
      }
    }
    uintx4 vr[4];
    #pragma unroll
    for (int it = 0; it < 4; ++it){
      int s8 = it*256 + tid, n = s8 >> 3, d0 = (s8 & 7)*8;
      vr[it] = *(const uintx4*)(Vb + ((size_t)b*Nn + n0c + n)*D + h*64 + d0);
    }
    asm volatile("s_waitcnt vmcnt(0)" ::: "memory");
    __syncthreads();                        // Ks (+Ps) resident
    // diag = 0.0625*|k|^2
    {
      int row = tid >> 1, half = tid & 1;
      float s = 0.f;
      for (int i = 0; i < 32; ++i){
        int d = half*32 + ((row + i) & 31);
        float x = bf2f(Ks[row*64 + d]);
        s += x*x;
      }
      float o = __shfl_xor(s, 1);
      if (half == 0) diag_s[row] = 0.0625f * (s + o);
    }
    // V transpose into Tv
    #pragma unroll
    for (int it = 0; it < 4; ++it){
      int s8 = it*256 + tid, n = s8 >> 3, d0 = (s8 & 7)*8;
      const unsigned short* us = (const unsigned short*)&vr[it];
      #pragma unroll
      for (int ii = 0; ii < 8; ++ii) Tv[(d0+ii)*136 + n] = us[ii];
    }
    // dd = K·P^T
    floatx4 acc[2][4] = {};
    #pragma unroll
    for (int ksl = 0; ksl < 2; ++ksl){
      bf16x8 af[2], bfr[4];
      #pragma unroll
      for (int m = 0; m < 2; ++m)
        af[m] = *(const bf16x8*)((const char*)Ks + (wave*32 + m*16 + fr)*128 + ksl*64 + kch*16);
      #pragma unroll
      for (int n = 0; n < 4; ++n)
        bfr[n] = *(const bf16x8*)((const char*)Ps + (n*16 + fr)*128 + ksl*64 + kch*16);
      #pragma unroll
      for (int m = 0; m < 2; ++m)
        #pragma unroll
        for (int n = 0; n < 4; ++n)
          acc[m][n] = __builtin_amdgcn_mfma_f32_16x16x32_bf16(af[m], bfr[n], acc[m][n], 0, 0, 0);
    }
    __syncthreads();                        // diag_s + Tv complete
    // e = ratio*exp(dd - diag) (stab deferred), transposed into Te[j][n]
    #pragma unroll
    for (int m = 0; m < 2; ++m)
    #pragma unroll
    for (int r = 0; r < 4; ++r){
      int row = wave*32 + m*16 + kch*4 + r;
      float dg = diag_s[row];
      #pragma unroll
      for (int n = 0; n < 4; ++n){
        float dd = CS * acc[m][n][r];
        mx = fmaxf(mx, dd);
        Te[(n*16 + fr)*136 + row] = f2bf(0.125f * __expf(dd - dg));
      }
    }
    __syncthreads();                        // Te complete
    // partial column sums (accumulate in regs across chunks)
    {
      int j = tid >> 2, part = tid & 3;
      float s = 0.f, s2 = 0.f;
      for (int i = 0; i < 32; ++i){
        s  += bf2f(Te[j*136 + part*32 + i]);
        s2 += bf2f(Tv[j*136 + part*32 + i]);
      }
      esum_r += s; vsum_r += s2;
    }
    // kv += e · v^T  (out 64j x 64d, K = 128 chunk rows)
    #pragma unroll
    for (int nc = 0; nc < 4; ++nc){
      bf16x8 af = *(const bf16x8*)((const char*)Te + (wave*16 + fr)*272 + nc*64 + kch*16);
      #pragma unroll
      for (int nf = 0; nf < 4; ++nf){
        bf16x8 bfr = *(const bf16x8*)((const char*)Tv + (nf*16 + fr)*272 + nc*64 + kch*16);
        acc_kv[nf] = __builtin_amdgcn_mfma_f32_16x16x32_bf16(af, bfr, acc_kv[nf], 0, 0, 0);
      }
    }
  }
  // epilogue: one atomic per quantity
  {
    int j = tid >> 2;
    float s = esum_r + __shfl_xor(esum_r, 1); s += __shfl_xor(s, 2);
    float s2 = vsum_r + __shfl_xor(vsum_r, 1); s2 += __shfl_xor(s2, 2);
    if ((tid & 3) == 0){
      atomicAdd(&esum[bh*64 + j], s);
      atomicAdd(&vsum[bh*64 + j], s2);
    }
  }
  #pragma unroll
  for (int off = 1; off < 64; off <<= 1) mx = fmaxf(mx, __shfl_xor(mx, off));
  if (lane == 0) wm[wave] = mx;
  __syncthreads();
  if (tid == 0) atomicMaxF(&stab[bh], fmaxf(fmaxf(wm[0],wm[1]), fmaxf(wm[2],wm[3])));
  #pragma unroll
  for (int nf = 0; nf < 4; ++nf)
  #pragma unroll
  for (int r = 0; r < 4; ++r){
    int j = wave*16 + kch*4 + r, d = nf*16 + fr;
    kvp[((size_t)(ksb*64 + bh)*64 + j)*64 + d] = acc_kv[nf][r];
  }
}

// reduce over KS, apply deferred stab + eps terms.
__global__ __launch_bounds__(256) void k_kvred(const float* __restrict__ kvp,
                                               const float* __restrict__ stab,
                                               const float* __restrict__ esum,
                                               const float* __restrict__ vsum,
                                               unsigned short* __restrict__ Kvt,
                                               float* __restrict__ ksumf){
  const int bh = blockIdx.x, tid = threadIdx.x;
  const float s = __expf(-stab[bh]);
  for (int i = 0; i < 16; ++i){
    int idx = i*256 + tid;
    int j = idx >> 6, d = idx & 63;
    float sum = 0.f;
    #pragma unroll
    for (int ks = 0; ks < 8; ++ks) sum += kvp[((size_t)(ks*64 + bh)*64 + j)*64 + d];
    Kvt[((size_t)bh*64 + d)*64 + j] = f2bf(s*sum + 1e-4f*vsum[bh*64 + d]);
  }
  if (tid < 64) ksumf[bh*64 + tid] = s*esum[bh*64 + tid] + 0.4096f;
}

// fused Q-side FAVOR + PV + normalize -> att
__global__ __launch_bounds__(256) void k_qattn(const unsigned short* __restrict__ Qb,
                                               const unsigned short* __restrict__ Pb,
                                               const unsigned short* __restrict__ Kvt,
                                               const float* __restrict__ ksumf,
                                               unsigned short* __restrict__ att,
                                               int Nn, int D, int H)
{
  __shared__ __align__(16) unsigned short Qs[128*64];
  __shared__ __align__(16) unsigned short Ps[64*64];
  __shared__ __align__(16) unsigned short Ks[64*64];
  __shared__ __align__(16) unsigned short Q2[128*64];
  __shared__ float ksum_s[64];
  __shared__ float diag_s[128];
  __shared__ float nrm[128];
  const int tid = threadIdx.x, wave = tid >> 6, lane = tid & 63;
  const int bh = blockIdx.y, h = bh % H, b = bh / H;
  const int n0 = blockIdx.x * 128;
  const int fr = lane & 15, kch = lane >> 4;
  const int sr = lane >> 3, sc = (lane & 7) * 8;
  #pragma unroll
  for (int q = 0; q < 4; ++q){
    int seg = wave*4 + q;
    gload_lds16(Qb + ((size_t)b*Nn + n0 + seg*8 + sr)*D + h*64 + sc, (char*)Qs + seg*1024);
  }
  #pragma unroll
  for (int q = 0; q < 2; ++q){
    int seg = wave*2 + q;
    gload_lds16(Pb + (size_t)h*4096 + seg*512 + lane*8, (char*)Ps + seg*1024);
    gload_lds16(Kvt + (size_t)bh*4096 + seg*512 + lane*8, (char*)Ks + seg*1024);
  }
  if (tid < 64) ksum_s[tid] = ksumf[bh*64 + tid];
  __syncthreads();
  {
    int row = tid >> 1, half = tid & 1;
    float s = 0.f;
    for (int i = 0; i < 32; ++i){
      int d = half*32 + ((row + i) & 31);
      float x = bf2f(Qs[row*64 + d]);
      s += x*x;
    }
    float o = __shfl_xor(s, 1);
    if (half == 0) diag_s[row] = 0.0625f * (s + o);
  }
  floatx4 acc[2][4] = {};
  #pragma unroll
  for (int ks = 0; ks < 2; ++ks){
    bf16x8 af[2], bfr[4];
    #pragma unroll
    for (int m = 0; m < 2; ++m)
      af[m] = *(const bf16x8*)((const char*)Qs + (wave*32 + m*16 + fr)*128 + ks*64 + kch*16);
    #pragma unroll
    for (int n = 0; n < 4; ++n)
      bfr[n] = *(const bf16x8*)((const char*)Ps + (n*16 + fr)*128 + ks*64 + kch*16);
    #pragma unroll
    for (int m = 0; m < 2; ++m)
      #pragma unroll
      for (int n = 0; n < 4; ++n)
        acc[m][n] = __builtin_amdgcn_mfma_f32_16x16x32_bf16(af[m], bfr[n], acc[m][n], 0, 0, 0);
  }
  __syncthreads();   // diag_s ready
  #pragma unroll
  for (int m = 0; m < 2; ++m)
  #pragma unroll
  for (int r = 0; r < 4; ++r){
    float mxv = -1e30f;
    #pragma unroll
    for (int n = 0; n < 4; ++n) mxv = fmaxf(mxv, acc[m][n][r]);
    mxv = fmaxf(mxv, __shfl_xor(mxv, 1));
    mxv = fmaxf(mxv, __shfl_xor(mxv, 2));
    mxv = fmaxf(mxv, __shfl_xor(mxv, 4));
    mxv = fmaxf(mxv, __shfl_xor(mxv, 8));
    int row = wave*32 + m*16 + kch*4 + r;
    float dg = diag_s[row];
    float stabv = CS * mxv;
    float qp[4], pr = 0.f;
    #pragma unroll
    for (int n = 0; n < 4; ++n){
      qp[n] = 0.125f * __expf(CS*acc[m][n][r] - dg - stabv) + 1e-4f;
      pr += qp[n] * ksum_s[n*16 + fr];
    }
    pr += __shfl_xor(pr, 1); pr += __shfl_xor(pr, 2);
    pr += __shfl_xor(pr, 4); pr += __shfl_xor(pr, 8);
    if (fr == 0) nrm[row] = fmaxf(pr, 0.01f);
    #pragma unroll
    for (int n = 0; n < 4; ++n){
      int j = n*16 + fr;
      int slot = (j >> 3) ^ (row & 7);
      ((unsigned short*)Q2)[row*64 + slot*8 + (j & 7)] = f2bf(qp[n]);
    }
  }
  __syncthreads();   // Q2 + nrm ready
  floatx4 acc2[2][4] = {};
  #pragma unroll
  for (int ks = 0; ks < 2; ++ks){
    bf16x8 af[2], bfr[4];
    #pragma unroll
    for (int m = 0; m < 2; ++m){
      int row = wave*32 + m*16 + fr;
      int slot = (ks*4 + kch) ^ (row & 7);
      af[m] = *(const bf16x8*)((const char*)Q2 + row*128 + slot*16);
    }
    #pragma unroll
    for (int n = 0; n < 4; ++n)
      bfr[n] = *(const bf16x8*)((const char*)Ks + (n*16 + fr)*128 + ks*64 + kch*16);
    #pragma unroll
    for (int m = 0; m < 2; ++m)
      #pragma unroll
      for (int n = 0; n < 4; ++n)
        acc2[m][n] = __builtin_amdgcn_mfma_f32_16x16x32_bf16(af[m], bfr[n], acc2[m][n], 0, 0, 0);
  }
  #pragma unroll
  for (int m = 0; m < 2; ++m)
  #pragma unroll
  for (int r = 0; r < 4; ++r){
    int row = wave*32 + m*16 + kch*4 + r;
    float inv = 1.0f / nrm[row];
    #pragma unroll
    for (int n = 0; n < 4; ++n){
      float v = acc2[m][n][r] * inv;
      att[((size_t)b*Nn + n0 + row)*D + h*64 + n*16 + fr] = f2bf(v);
    }
  }
}

extern "C" void kernel_launch(void* const* d_in, const int* in_sizes, int n_in,
                              void* d_out, int out_size, void* d_ws, size_t ws_size,
                              hipStream_t stream)
{
  (void)in_sizes; (void)n_in; (void)out_size; (void)ws_size;
  const float* query = (const float*)d_in[0];
  const float* Wq = (const float*)d_in[1];
  const float* bq = (const float*)d_in[2];
  const float* Wk = (const float*)d_in[3];
  const float* bk = (const float*)d_in[4];
  const float* Wv = (const float*)d_in[5];
  const float* bv = (const float*)d_in[6];
  const float* Wo = (const float*)d_in[7];
  const float* bo = (const float*)d_in[8];
  const float* proj = (const float*)d_in[9];

  const int B = 4, N = 4096, D = 1024, H = 16;
  const size_t NT = (size_t)B*N*D;

  char* ws = (char*)d_ws;
  unsigned short* qbf = (unsigned short*)ws;               // NT bf16 (later: att)
  unsigned short* wqb = (unsigned short*)(ws + 33554432);
  unsigned short* wkb = wqb + 1048576;
  unsigned short* wvb = wkb + 1048576;
  unsigned short* wob = wvb + 1048576;
  unsigned short* pjb = wob + 1048576;                     // 65536
  unsigned short* qb  = pjb + 65536;                       // NT
  unsigned short* kb  = qb + NT;                           // NT
  unsigned short* vb  = kb + NT;                           // NT
  float* kvp  = (float*)(vb + NT);                         // 8*64*64*64
  unsigned short* kvt = (unsigned short*)(kvp + 2097152);  // 64*64*64
  float* esum = (float*)(kvt + 262144);                    // 4096
  float* vsum = esum + 4096;                               // 4096
  float* ksumf = vsum + 4096;                              // 4096
  float* stab = ksumf + 4096;                              // 64
  unsigned short* att = qbf;

  k_prep<<<1297, 256, 0, stream>>>(query, Wq, Wk, Wv, Wo, proj,
                                   qbf, wqb, wkb, wvb, wob, pjb, esum, vsum, stab);

  gemm256<0><<<768, 512, 0, stream>>>(qbf, wqb, bq, bk, bv,
                                      qb, kb, vb, nullptr, B*N, 3072, D);

  k_fkv<<<dim3(8, 64), 256, 0, stream>>>(kb, vb, pjb, kvp, esum, vsum, stab, N, D, H);
  k_kvred<<<64, 256, 0, stream>>>(kvp, stab, esum, vsum, kvt, ksumf);
  k_qattn<<<dim3(32, 64), 256, 0, stream>>>(qb, pjb, kvt, ksumf, att, N, D, H);

  gemm256<1><<<256, 512, 0, stream>>>(att, wob, bo, nullptr, nullptr,
                                      nullptr, nullptr, nullptr,
                                      (float*)d_out, B*N, 1024, D);
}

// Round 8
// 215.146 us; speedup vs baseline: 1.0168x; 1.0168x over previous
//
#include <hip/hip_runtime.h>
#include <hip/hip_bf16.h>

using floatx4 = __attribute__((ext_vector_type(4))) float;
using bf16x8  = __attribute__((ext_vector_type(8))) __bf16;
using uintx4  = __attribute__((ext_vector_type(4))) unsigned int;

#define DEV __device__ __forceinline__

DEV unsigned short f2bf(float f){
  unsigned u = __float_as_uint(f);
  u = (u + 0x7FFFu + ((u >> 16) & 1u)) >> 16;   // RNE
  return (unsigned short)u;
}
DEV float bf2f(unsigned short h){ return __uint_as_float(((unsigned)h) << 16); }

DEV void gload_lds16(const void* g, void* l){
  __builtin_amdgcn_global_load_lds((const __attribute__((address_space(1))) void*)g,
                                   (__attribute__((address_space(3))) void*)l, 16, 0, 0);
}

DEV void atomicMaxF(float* a, float v){
  if (v >= 0.f) atomicMax((int*)a, __float_as_int(v));
  else          atomicMin((unsigned int*)a, __float_as_uint(v));
}

#define SBAR do{ __builtin_amdgcn_sched_barrier(0); __builtin_amdgcn_s_barrier(); \
                 __builtin_amdgcn_sched_barrier(0); }while(0)

// ---------------------------------------------------------------------------
// prep: all f32->bf16 casts + zero-init, one launch.
__global__ __launch_bounds__(256) void k_prep(
    const float* __restrict__ query, const float* __restrict__ Wq,
    const float* __restrict__ Wk, const float* __restrict__ Wv,
    const float* __restrict__ Wo, const float* __restrict__ proj,
    unsigned short* __restrict__ qbf, unsigned short* __restrict__ wqb,
    unsigned short* __restrict__ wkb, unsigned short* __restrict__ wvb,
    unsigned short* __restrict__ wob, unsigned short* __restrict__ pjb,
    float* __restrict__ esum, float* __restrict__ vsum, float* __restrict__ stab)
{
  const int bid = blockIdx.x, tid = threadIdx.x;
  const float* s; unsigned short* d; int i, stride, n4;
  if (bid < 1024){ s = query; d = qbf; i = bid*256 + tid; stride = 262144; n4 = 4194304; }
  else if (bid < 1280){
    int w = (bid - 1024) >> 6;
    s = (w==0)?Wq:(w==1)?Wk:(w==2)?Wv:Wo;
    d = (w==0)?wqb:(w==1)?wkb:(w==2)?wvb:wob;
    i = ((bid-1024)&63)*256 + tid; stride = 16384; n4 = 262144;
  } else if (bid < 1296){ s = proj; d = pjb; i = (bid-1280)*256 + tid; stride = 4096; n4 = 16384; }
  else {
    for (int k = tid; k < 4096; k += 256){ esum[k] = 0.f; vsum[k] = 0.f; }
    if (tid < 64) stab[tid] = -1e30f;
    return;
  }
  for (; i < n4; i += stride){
    float4 v = ((const float4*)s)[i];
    ushort4 o;
    o.x = f2bf(v.x); o.y = f2bf(v.y); o.z = f2bf(v.z); o.w = f2bf(v.w);
    ((ushort4*)d)[i] = o;
  }
}

// ---------------------------------------------------------------------------
// 256x256 GEMM, BK=64, 2 LDS buffers, 4 phases/K-tile, per-phase stage units,
// counted vmcnt(4), XOR slot swizzle, LDS-staged epilogue. 2D grid (x=m
// fastest): blocks sharing an A-panel land on the same XCD (64%8==0).
// OUTMODE 1 uses nontemporal stores (d_out never re-read).
template<int OUTMODE>
__global__ __launch_bounds__(512, 1) void gemm256(
    const unsigned short* __restrict__ A,
    const unsigned short* __restrict__ W,
    const float* __restrict__ bias0, const float* __restrict__ bias1,
    const float* __restrict__ bias2,
    unsigned short* __restrict__ out0, unsigned short* __restrict__ out1,
    unsigned short* __restrict__ out2,
    float* __restrict__ outf, int M, int Nout, int K)
{
  __shared__ __align__(16) char lds[131072];
  const int tid  = threadIdx.x;
  const int wid  = tid >> 6, lane = tid & 63;
  const int wr   = wid >> 2, wc = wid & 3;
  const int fr   = lane & 15, kch = lane >> 4;
  const int m0   = blockIdx.x * 256, n0 = blockIdx.y * 256;
  const int NU   = (K >> 6) * 4;                  // total stage units
  const size_t Kb = (size_t)K * 2;

  // staging lane constants: 4 lanes/row (64B khalf), swizzled source slot
  const int ssw = (((lane & 3) ^ ((lane >> 3) & 3))) * 16;
  const char* Arow = (const char*)A + (size_t)(m0 + wid*16 + (lane >> 2))*Kb + ssw;
  const char* Brow = (const char*)W + (size_t)(n0 + wid*16 + (lane >> 2))*Kb + ssw;

  auto stage = [&](int u){
    if (u >= NU) return;
    int T = u >> 2, q = u & 3, isB = q & 1, s = q >> 1;
    char* dst = lds + (T & 1)*65536 + isB*32768 + s*16384 + wid*1024;
    const char* src = (isB ? Brow : Arow) + (size_t)T*128 + s*64;
    gload_lds16(src, dst);
    gload_lds16(src + 128*Kb, dst + 8192);
  };

  // prologue: tile 0's 4 units (8 loads/wave)
  stage(0); stage(1); stage(2); stage(3);

  const int rkey = (fr >> 1) & 3;
  const int aBase = (wr*128 + fr)*64 + (kch ^ rkey)*16;
  const int bBase = 32768 + (wc*64 + fr)*64 + (kch ^ rkey)*16;
  floatx4 acc[8][4] = {};
  bf16x8 a[4], bq[4];

  const int NTt = K >> 6;
  for (int T = 0; T < NTt; ++T){
    const char* buf = lds + (T & 1)*65536;
    // ---- phase 0: s=0, mt 0-3 (+ B s0)
    asm volatile("s_waitcnt vmcnt(4)" ::: "memory");
    SBAR;
    #pragma unroll
    for (int mt = 0; mt < 4; ++mt) a[mt]  = *(const bf16x8*)(buf + aBase + mt*1024);
    #pragma unroll
    for (int nt = 0; nt < 4; ++nt) bq[nt] = *(const bf16x8*)(buf + bBase + nt*1024);
    stage(T*4 + 4);
    __builtin_amdgcn_s_setprio(1);
    #pragma unroll
    for (int mt = 0; mt < 4; ++mt)
      #pragma unroll
      for (int nt = 0; nt < 4; ++nt)
        acc[mt][nt] = __builtin_amdgcn_mfma_f32_16x16x32_bf16(a[mt], bq[nt], acc[mt][nt], 0, 0, 0);
    __builtin_amdgcn_s_setprio(0);
    // ---- phase 1: s=0, mt 4-7
    #pragma unroll
    for (int mt = 0; mt < 4; ++mt) a[mt] = *(const bf16x8*)(buf + aBase + (4+mt)*1024);
    stage(T*4 + 5);
    __builtin_amdgcn_s_setprio(1);
    #pragma unroll
    for (int mt = 0; mt < 4; ++mt)
      #pragma unroll
      for (int nt = 0; nt < 4; ++nt)
        acc[4+mt][nt] = __builtin_amdgcn_mfma_f32_16x16x32_bf16(a[mt], bq[nt], acc[4+mt][nt], 0, 0, 0);
    __builtin_amdgcn_s_setprio(0);
    // ---- phase 2: s=1, mt 0-3 (+ B s1)
    if (T + 1 < NTt) asm volatile("s_waitcnt vmcnt(4)" ::: "memory");
    else             asm volatile("s_waitcnt vmcnt(0)" ::: "memory");
    SBAR;
    #pragma unroll
    for (int mt = 0; mt < 4; ++mt) a[mt]  = *(const bf16x8*)(buf + 16384 + aBase + mt*1024);
    #pragma unroll
    for (int nt = 0; nt < 4; ++nt) bq[nt] = *(const bf16x8*)(buf + 16384 + bBase + nt*1024);
    stage(T*4 + 6);
    __builtin_amdgcn_s_setprio(1);
    #pragma unroll
    for (int mt = 0; mt < 4; ++mt)
      #pragma unroll
      for (int nt = 0; nt < 4; ++nt)
        acc[mt][nt] = __builtin_amdgcn_mfma_f32_16x16x32_bf16(a[mt], bq[nt], acc[mt][nt], 0, 0, 0);
    __builtin_amdgcn_s_setprio(0);
    // ---- phase 3: s=1, mt 4-7
    #pragma unroll
    for (int mt = 0; mt < 4; ++mt) a[mt] = *(const bf16x8*)(buf + 16384 + aBase + (4+mt)*1024);
    stage(T*4 + 7);
    __builtin_amdgcn_s_setprio(1);
    #pragma unroll
    for (int mt = 0; mt < 4; ++mt)
      #pragma unroll
      for (int nt = 0; nt < 4; ++nt)
        acc[4+mt][nt] = __builtin_amdgcn_mfma_f32_16x16x32_bf16(a[mt], bq[nt], acc[4+mt][nt], 0, 0, 0);
    __builtin_amdgcn_s_setprio(0);
  }

  // ---- epilogue: stage through LDS for full-line global writes.
  SBAR;
  if (OUTMODE == 0){
    const int which = n0 >> 10;
    const float* bb = (which == 0) ? bias0 : (which == 1) ? bias1 : bias2;
    unsigned short* oo = (which == 0) ? out0 : (which == 1) ? out1 : out2;
    unsigned short* Lt = (unsigned short*)lds;   // [256][256] bf16, col-XOR swz
    #pragma unroll
    for (int nf = 0; nf < 4; ++nf){
      int col = wc*64 + nf*16 + fr;
      float bv = bb[(n0 + col) & 1023];
      #pragma unroll
      for (int mf = 0; mf < 8; ++mf)
        #pragma unroll
        for (int r = 0; r < 4; ++r){
          int row = wr*128 + mf*16 + kch*4 + r;
          Lt[row*256 + (col ^ (((row >> 2) & 3) << 4))] = f2bf(acc[mf][nf][r] + bv);
        }
    }
    SBAR;
    const int orow = tid >> 5, oj = tid & 31;
    #pragma unroll
    for (int p = 0; p < 16; ++p){
      int row = p*16 + orow;
      uintx4 v = *(const uintx4*)(Lt + row*256 + ((oj*8) ^ (((row >> 2) & 3) << 4)));
      *(uintx4*)(oo + (size_t)(m0 + row)*1024 + (n0 & 1023) + oj*8) = v;
    }
  } else {
    float* Lf = (float*)lds;                     // [128][256] f32, 2 passes
    #pragma unroll
    for (int p = 0; p < 2; ++p){
      if (wr == p){
        #pragma unroll
        for (int nf = 0; nf < 4; ++nf){
          int col = wc*64 + nf*16 + fr;
          float bv = bias0[n0 + col];
          #pragma unroll
          for (int mf = 0; mf < 8; ++mf)
            #pragma unroll
            for (int r = 0; r < 4; ++r){
              int row = mf*16 + kch*4 + r;       // 0..127
              Lf[row*256 + (col ^ (((row >> 2) & 3) << 4))] = acc[mf][nf][r] + bv;
            }
        }
      }
      SBAR;
      const int oj = tid & 63;
      #pragma unroll
      for (int pp = 0; pp < 16; ++pp){
        int row = pp*8 + wid;
        uintx4 v = *(const uintx4*)(Lf + row*256 + ((oj*4) ^ (((row >> 2) & 3) << 4)));
        __builtin_nontemporal_store(v,
            (uintx4*)(outf + (size_t)(m0 + p*128 + row)*Nout + n0 + oj*4));
      }
      SBAR;
    }
  }
}

// ---- FAVOR+ -----------------------------------------------------------------
#define CS 0.35355339059327373f   /* 64^-0.25 */

// Fused K-side FAVOR + V-transpose + kv-contraction. Block = (ks, bh); loops
// 4 chunks of 128 rows. e-features and V^T live only in LDS; kv partials
// accumulate in registers across chunks. Writes: kvp[ks][bh][64][64] f32 only.
__global__ __launch_bounds__(256) void k_fkv(const unsigned short* __restrict__ Kb,
                                             const unsigned short* __restrict__ Vb,
                                             const unsigned short* __restrict__ Pb,
                                             float* __restrict__ kvp,
                                             float* __restrict__ esum,
                                             float* __restrict__ vsum,
                                             float* __restrict__ stab,
                                             int Nn, int D, int H)
{
  __shared__ __align__(16) unsigned short Ks[128*64];
  __shared__ __align__(16) unsigned short Ps[64*64];
  __shared__ __align__(16) unsigned short Te[64*136];
  __shared__ __align__(16) unsigned short Tv[64*136];
  __shared__ float diag_s[128];
  __shared__ float wm[4];
  const int tid = threadIdx.x, wave = tid >> 6, lane = tid & 63;
  const int ksb = blockIdx.x, bh = blockIdx.y, h = bh % H, b = bh / H;
  const int fr = lane & 15, kch = lane >> 4;
  const int sr = lane >> 3, sc = (lane & 7) * 8;
  float esum_r = 0.f, vsum_r = 0.f, mx = -1e30f;
  floatx4 acc_kv[4] = {};

  for (int c = 0; c < 4; ++c){
    const int n0c = ksb*512 + c*128;
    __syncthreads();                        // prev chunk fully consumed
    #pragma unroll
    for (int q = 0; q < 4; ++q){
      int seg = wave*4 + q;
      gload_lds16(Kb + ((size_t)b*Nn + n0c + seg*8 + sr)*D + h*64 + sc, (char*)Ks + seg*1024);
    }
    if (c == 0){
      #pragma unroll
      for (int q = 0; q < 2; ++q){
        int seg = wave*2 + q;
        gload_lds16(Pb + (size_t)h*4096 + seg*512 + lane*8, (char*)Ps + seg*1024);
      }
    }
    uintx4 vr[4];
    #pragma unroll
    for (int it = 0; it < 4; ++it){
      int s8 = it*256 + tid, n = s8 >> 3, d0 = (s8 & 7)*8;
      vr[it] = *(const uintx4*)(Vb + ((size_t)b*Nn + n0c + n)*D + h*64 + d0);
    }
    asm volatile("s_waitcnt vmcnt(0)" ::: "memory");
    __syncthreads();                        // Ks (+Ps) resident
    // diag = 0.0625*|k|^2
    {
      int row = tid >> 1, half = tid & 1;
      float s = 0.f;
      for (int i = 0; i < 32; ++i){
        int d = half*32 + ((row + i) & 31);
        float x = bf2f(Ks[row*64 + d]);
        s += x*x;
      }
      float o = __shfl_xor(s, 1);
      if (half == 0) diag_s[row] = 0.0625f * (s + o);
    }
    // V transpose into Tv
    #pragma unroll
    for (int it = 0; it < 4; ++it){
      int s8 = it*256 + tid, n = s8 >> 3, d0 = (s8 & 7)*8;
      const unsigned short* us = (const unsigned short*)&vr[it];
      #pragma unroll
      for (int ii = 0; ii < 8; ++ii) Tv[(d0+ii)*136 + n] = us[ii];
    }
    // dd = K·P^T
    floatx4 acc[2][4] = {};
    #pragma unroll
    for (int ksl = 0; ksl < 2; ++ksl){
      bf16x8 af[2], bfr[4];
      #pragma unroll
      for (int m = 0; m < 2; ++m)
        af[m] = *(const bf16x8*)((const char*)Ks + (wave*32 + m*16 + fr)*128 + ksl*64 + kch*16);
      #pragma unroll
      for (int n = 0; n < 4; ++n)
        bfr[n] = *(const bf16x8*)((const char*)Ps + (n*16 + fr)*128 + ksl*64 + kch*16);
      #pragma unroll
      for (int m = 0; m < 2; ++m)
        #pragma unroll
        for (int n = 0; n < 4; ++n)
          acc[m][n] = __builtin_amdgcn_mfma_f32_16x16x32_bf16(af[m], bfr[n], acc[m][n], 0, 0, 0);
    }
    __syncthreads();                        // diag_s + Tv complete
    // e = ratio*exp(dd - diag) (stab deferred), transposed into Te[j][n]
    #pragma unroll
    for (int m = 0; m < 2; ++m)
    #pragma unroll
    for (int r = 0; r < 4; ++r){
      int row = wave*32 + m*16 + kch*4 + r;
      float dg = diag_s[row];
      #pragma unroll
      for (int n = 0; n < 4; ++n){
        float dd = CS * acc[m][n][r];
        mx = fmaxf(mx, dd);
        Te[(n*16 + fr)*136 + row] = f2bf(0.125f * __expf(dd - dg));
      }
    }
    __syncthreads();                        // Te complete
    // partial column sums (accumulate in regs across chunks)
    {
      int j = tid >> 2, part = tid & 3;
      float s = 0.f, s2 = 0.f;
      for (int i = 0; i < 32; ++i){
        s  += bf2f(Te[j*136 + part*32 + i]);
        s2 += bf2f(Tv[j*136 + part*32 + i]);
      }
      esum_r += s; vsum_r += s2;
    }
    // kv += e · v^T  (out 64j x 64d, K = 128 chunk rows)
    #pragma unroll
    for (int nc = 0; nc < 4; ++nc){
      bf16x8 af = *(const bf16x8*)((const char*)Te + (wave*16 + fr)*272 + nc*64 + kch*16);
      #pragma unroll
      for (int nf = 0; nf < 4; ++nf){
        bf16x8 bfr = *(const bf16x8*)((const char*)Tv + (nf*16 + fr)*272 + nc*64 + kch*16);
        acc_kv[nf] = __builtin_amdgcn_mfma_f32_16x16x32_bf16(af, bfr, acc_kv[nf], 0, 0, 0);
      }
    }
  }
  // epilogue: one atomic per quantity
  {
    int j = tid >> 2;
    float s = esum_r + __shfl_xor(esum_r, 1); s += __shfl_xor(s, 2);
    float s2 = vsum_r + __shfl_xor(vsum_r, 1); s2 += __shfl_xor(s2, 2);
    if ((tid & 3) == 0){
      atomicAdd(&esum[bh*64 + j], s);
      atomicAdd(&vsum[bh*64 + j], s2);
    }
  }
  #pragma unroll
  for (int off = 1; off < 64; off <<= 1) mx = fmaxf(mx, __shfl_xor(mx, off));
  if (lane == 0) wm[wave] = mx;
  __syncthreads();
  if (tid == 0) atomicMaxF(&stab[bh], fmaxf(fmaxf(wm[0],wm[1]), fmaxf(wm[2],wm[3])));
  #pragma unroll
  for (int nf = 0; nf < 4; ++nf)
  #pragma unroll
  for (int r = 0; r < 4; ++r){
    int j = wave*16 + kch*4 + r, d = nf*16 + fr;
    kvp[((size_t)(ksb*64 + bh)*64 + j)*64 + d] = acc_kv[nf][r];
  }
}

// reduce over KS, apply deferred stab + eps terms.
__global__ __launch_bounds__(256) void k_kvred(const float* __restrict__ kvp,
                                               const float* __restrict__ stab,
                                               const float* __restrict__ esum,
                                               const float* __restrict__ vsum,
                                               unsigned short* __restrict__ Kvt,
                                               float* __restrict__ ksumf){
  const int bh = blockIdx.x, tid = threadIdx.x;
  const float s = __expf(-stab[bh]);
  for (int i = 0; i < 16; ++i){
    int idx = i*256 + tid;
    int j = idx >> 6, d = idx & 63;
    float sum = 0.f;
    #pragma unroll
    for (int ks = 0; ks < 8; ++ks) sum += kvp[((size_t)(ks*64 + bh)*64 + j)*64 + d];
    Kvt[((size_t)bh*64 + d)*64 + j] = f2bf(s*sum + 1e-4f*vsum[bh*64 + d]);
  }
  if (tid < 64) ksumf[bh*64 + tid] = s*esum[bh*64 + tid] + 0.4096f;
}

// fused Q-side FAVOR + PV + normalize -> att
__global__ __launch_bounds__(256) void k_qattn(const unsigned short* __restrict__ Qb,
                                               const unsigned short* __restrict__ Pb,
                                               const unsigned short* __restrict__ Kvt,
                                               const float* __restrict__ ksumf,
                                               unsigned short* __restrict__ att,
                                               int Nn, int D, int H)
{
  __shared__ __align__(16) unsigned short Qs[128*64];
  __shared__ __align__(16) unsigned short Ps[64*64];
  __shared__ __align__(16) unsigned short Ks[64*64];
  __shared__ __align__(16) unsigned short Q2[128*64];
  __shared__ float ksum_s[64];
  __shared__ float diag_s[128];
  __shared__ float nrm[128];
  const int tid = threadIdx.x, wave = tid >> 6, lane = tid & 63;
  const int bh = blockIdx.y, h = bh % H, b = bh / H;
  const int n0 = blockIdx.x * 128;
  const int fr = lane & 15, kch = lane >> 4;
  const int sr = lane >> 3, sc = (lane & 7) * 8;
  #pragma unroll
  for (int q = 0; q < 4; ++q){
    int seg = wave*4 + q;
    gload_lds16(Qb + ((size_t)b*Nn + n0 + seg*8 + sr)*D + h*64 + sc, (char*)Qs + seg*1024);
  }
  #pragma unroll
  for (int q = 0; q < 2; ++q){
    int seg = wave*2 + q;
    gload_lds16(Pb + (size_t)h*4096 + seg*512 + lane*8, (char*)Ps + seg*1024);
    gload_lds16(Kvt + (size_t)bh*4096 + seg*512 + lane*8, (char*)Ks + seg*1024);
  }
  if (tid < 64) ksum_s[tid] = ksumf[bh*64 + tid];
  __syncthreads();
  {
    int row = tid >> 1, half = tid & 1;
    float s = 0.f;
    for (int i = 0; i < 32; ++i){
      int d = half*32 + ((row + i) & 31);
      float x = bf2f(Qs[row*64 + d]);
      s += x*x;
    }
    float o = __shfl_xor(s, 1);
    if (half == 0) diag_s[row] = 0.0625f * (s + o);
  }
  floatx4 acc[2][4] = {};
  #pragma unroll
  for (int ks = 0; ks < 2; ++ks){
    bf16x8 af[2], bfr[4];
    #pragma unroll
    for (int m = 0; m < 2; ++m)
      af[m] = *(const bf16x8*)((const char*)Qs + (wave*32 + m*16 + fr)*128 + ks*64 + kch*16);
    #pragma unroll
    for (int n = 0; n < 4; ++n)
      bfr[n] = *(const bf16x8*)((const char*)Ps + (n*16 + fr)*128 + ks*64 + kch*16);
    #pragma unroll
    for (int m = 0; m < 2; ++m)
      #pragma unroll
      for (int n = 0; n < 4; ++n)
        acc[m][n] = __builtin_amdgcn_mfma_f32_16x16x32_bf16(af[m], bfr[n], acc[m][n], 0, 0, 0);
  }
  __syncthreads();   // diag_s ready
  #pragma unroll
  for (int m = 0; m < 2; ++m)
  #pragma unroll
  for (int r = 0; r < 4; ++r){
    float mxv = -1e30f;
    #pragma unroll
    for (int n = 0; n < 4; ++n) mxv = fmaxf(mxv, acc[m][n][r]);
    mxv = fmaxf(mxv, __shfl_xor(mxv, 1));
    mxv = fmaxf(mxv, __shfl_xor(mxv, 2));
    mxv = fmaxf(mxv, __shfl_xor(mxv, 4));
    mxv = fmaxf(mxv, __shfl_xor(mxv, 8));
    int row = wave*32 + m*16 + kch*4 + r;
    float dg = diag_s[row];
    float stabv = CS * mxv;
    float qp[4], pr = 0.f;
    #pragma unroll
    for (int n = 0; n < 4; ++n){
      qp[n] = 0.125f * __expf(CS*acc[m][n][r] - dg - stabv) + 1e-4f;
      pr += qp[n] * ksum_s[n*16 + fr];
    }
    pr += __shfl_xor(pr, 1); pr += __shfl_xor(pr, 2);
    pr += __shfl_xor(pr, 4); pr += __shfl_xor(pr, 8);
    if (fr == 0) nrm[row] = fmaxf(pr, 0.01f);
    #pragma unroll
    for (int n = 0; n < 4; ++n){
      int j = n*16 + fr;
      int slot = (j >> 3) ^ (row & 7);
      ((unsigned short*)Q2)[row*64 + slot*8 + (j & 7)] = f2bf(qp[n]);
    }
  }
  __syncthreads();   // Q2 + nrm ready
  floatx4 acc2[2][4] = {};
  #pragma unroll
  for (int ks = 0; ks < 2; ++ks){
    bf16x8 af[2], bfr[4];
    #pragma unroll
    for (int m = 0; m < 2; ++m){
      int row = wave*32 + m*16 + fr;
      int slot = (ks*4 + kch) ^ (row & 7);
      af[m] = *(const bf16x8*)((const char*)Q2 + row*128 + slot*16);
    }
    #pragma unroll
    for (int n = 0; n < 4; ++n)
      bfr[n] = *(const bf16x8*)((const char*)Ks + (n*16 + fr)*128 + ks*64 + kch*16);
    #pragma unroll
    for (int m = 0; m < 2; ++m)
      #pragma unroll
      for (int n = 0; n < 4; ++n)
        acc2[m][n] = __builtin_amdgcn_mfma_f32_16x16x32_bf16(af[m], bfr[n], acc2[m][n], 0, 0, 0);
  }
  #pragma unroll
  for (int m = 0; m < 2; ++m)
  #pragma unroll
  for (int r = 0; r < 4; ++r){
    int row = wave*32 + m*16 + kch*4 + r;
    float inv = 1.0f / nrm[row];
    #pragma unroll
    for (int n = 0; n < 4; ++n){
      float v = acc2[m][n][r] * inv;
      att[((size_t)b*Nn + n0 + row)*D + h*64 + n*16 + fr] = f2bf(v);
    }
  }
}

extern "C" void kernel_launch(void* const* d_in, const int* in_sizes, int n_in,
                              void* d_out, int out_size, void* d_ws, size_t ws_size,
                              hipStream_t stream)
{
  (void)in_sizes; (void)n_in; (void)out_size; (void)ws_size;
  const float* query = (const float*)d_in[0];
  const float* Wq = (const float*)d_in[1];
  const float* bq = (const float*)d_in[2];
  const float* Wk = (const float*)d_in[3];
  const float* bk = (const float*)d_in[4];
  const float* Wv = (const float*)d_in[5];
  const float* bv = (const float*)d_in[6];
  const float* Wo = (const float*)d_in[7];
  const float* bo = (const float*)d_in[8];
  const float* proj = (const float*)d_in[9];

  const int B = 4, N = 4096, D = 1024, H = 16;
  const size_t NT = (size_t)B*N*D;

  char* ws = (char*)d_ws;
  unsigned short* qbf = (unsigned short*)ws;               // NT bf16 (later: att)
  unsigned short* wqb = (unsigned short*)(ws + 33554432);
  unsigned short* wkb = wqb + 1048576;
  unsigned short* wvb = wkb + 1048576;
  unsigned short* wob = wvb + 1048576;
  unsigned short* pjb = wob + 1048576;                     // 65536
  unsigned short* qb  = pjb + 65536;                       // NT
  unsigned short* kb  = qb + NT;                           // NT
  unsigned short* vb  = kb + NT;                           // NT
  float* kvp  = (float*)(vb + NT);                         // 8*64*64*64
  unsigned short* kvt = (unsigned short*)(kvp + 2097152);  // 64*64*64
  float* esum = (float*)(kvt + 262144);                    // 4096
  float* vsum = esum + 4096;                               // 4096
  float* ksumf = vsum + 4096;                              // 4096
  float* stab = ksumf + 4096;                              // 64
  unsigned short* att = qbf;

  k_prep<<<1297, 256, 0, stream>>>(query, Wq, Wk, Wv, Wo, proj,
                                   qbf, wqb, wkb, wvb, wob, pjb, esum, vsum, stab);

  gemm256<0><<<dim3(64, 12), 512, 0, stream>>>(qbf, wqb, bq, bk, bv,
                                               qb, kb, vb, nullptr, B*N, 3072, D);

  k_fkv<<<dim3(8, 64), 256, 0, stream>>>(kb, vb, pjb, kvp, esum, vsum, stab, N, D, H);
  k_kvred<<<64, 256, 0, stream>>>(kvp, stab, esum, vsum, kvt, ksumf);
  k_qattn<<<dim3(32, 64), 256, 0, stream>>>(qb, pjb, kvt, ksumf, att, N, D, H);

  gemm256<1><<<dim3(64, 4), 512, 0, stream>>>(att, wob, bo, nullptr, nullptr,
                                              nullptr, nullptr, nullptr,
                                              (float*)d_out, B*N, 1024, D);
}